// Round 12
// baseline (272.588 us; speedup 1.0000x reference)
//
#include <hip/hip_runtime.h>

// Problem constants
#define NB 16
#define NH 96
#define NW 320
#define NCIN 32

typedef __attribute__((ext_vector_type(8))) short short8;     // 8 bf16 (4 VGPRs)
typedef __attribute__((ext_vector_type(4))) float f32x4;

__device__ inline unsigned short f2bf(float f) {
    union { float f; unsigned int u; } v; v.f = f;
    unsigned int r = v.u + 0x7FFF + ((v.u >> 16) & 1);   // RNE
    return (unsigned short)(r >> 16);
}

// ---------------------------------------------------------------------------
// Fused setup kernel.
// Blocks [0,396): weight fragments OIHW fp32 -> MFMA B-operand bf16,
//   wf[((kk*NT + nt)*64 + lane)*8 + j], oc = nt*16+(lane&15),
//   ic = ks*32+(lane>>4)*8+j  [m91-verified map]
// Blocks [396,...): scatter+cast active cells from fp32 input into the
//   (memset-zeroed) dense bf16 input. Reads ONLY active cells (~25.6 MB).
// ---------------------------------------------------------------------------
__global__ __launch_bounds__(256) void setup_all(const float* __restrict__ w1,
                                                 const float* __restrict__ w2,
                                                 const float* __restrict__ w3,
                                                 unsigned short* __restrict__ f1,
                                                 unsigned short* __restrict__ f2,
                                                 unsigned short* __restrict__ f3,
                                                 const int* __restrict__ coords,
                                                 const float* __restrict__ input,
                                                 unsigned short* __restrict__ inBf,
                                                 int n) {
    if (blockIdx.x < 396) {
        int i = blockIdx.x * 256 + threadIdx.x;
        if (i < 9216) {                       // conv1: IC=32 OC=32 NT=2 KS=1
            int j = i & 7, lane = (i >> 3) & 63, nt = (i >> 9) & 1, tap = i >> 10;
            int ic = ((lane >> 4) * 8) + j, oc = nt * 16 + (lane & 15);
            f1[i] = f2bf(w1[(oc * 32 + ic) * 9 + tap]);
        } else if (i < 27648) {               // conv2: IC=32 OC=64 NT=4 KS=1
            int v = i - 9216;
            int j = v & 7, lane = (v >> 3) & 63, nt = (v >> 9) & 3, tap = v >> 11;
            int ic = ((lane >> 4) * 8) + j, oc = nt * 16 + (lane & 15);
            f2[v] = f2bf(w2[(oc * 32 + ic) * 9 + tap]);
        } else if (i < 101376) {              // conv3: IC=64 OC=128 NT=8 KS=2
            int v = i - 27648;
            int j = v & 7, lane = (v >> 3) & 63, nt = (v >> 9) & 7, kk = v >> 12;
            int tap = kk >> 1, ks = kk & 1;
            int ic = ks * 32 + ((lane >> 4) * 8) + j, oc = nt * 16 + (lane & 15);
            f3[v] = f2bf(w3[(oc * 64 + ic) * 9 + tap]);
        }
    } else {
        int i = (blockIdx.x - 396) * 256 + threadIdx.x;
        if (i >= n * 4) return;
        int ci = i >> 2, q = i & 3;
        int b = coords[ci * 3 + 0], y = coords[ci * 3 + 1], x = coords[ci * 3 + 2];
        long base = ((long)((b * NH + y) * NW + x)) * NCIN + q * 8;
        const float4* src = (const float4*)(input + base);
        float4 v0 = src[0], v1 = src[1];
        union { short8 s8; unsigned short us[8]; } o;
        o.us[0] = f2bf(v0.x); o.us[1] = f2bf(v0.y); o.us[2] = f2bf(v0.z); o.us[3] = f2bf(v0.w);
        o.us[4] = f2bf(v1.x); o.us[5] = f2bf(v1.y); o.us[6] = f2bf(v1.z); o.us[7] = f2bf(v1.w);
        *(short8*)(inBf + base) = o.s8;
    }
}

// ---------------------------------------------------------------------------
// Implicit-GEMM conv 3x3 stride-2 pad-1 via bf16 MFMA (16x16x32), bf16 NHWC in.
// Each wave: one 16-position strip x NL oc-tiles. A-fragments loaded ONCE
// per ks (9 x 16 B/lane, unconditional, addr clamped to cell 0, reg-reg
// cndmask -- R8 lesson), reused for NL*9 MFMAs (R9/R10 lesson). B-frag loads
// coalesced 1KB/wave, L1-hot, in-loop. acc indices compile-time (R4), ks loop
// unroll 1 (R2). Layouts m89/m91.
// ---------------------------------------------------------------------------
template<int IC, int OC, int NL, int IH, int IW, int OH, int OW>
__global__ __launch_bounds__(256) void conv_mfma(
    const unsigned short* __restrict__ inPtr,  // NHWC bf16
    const unsigned short* __restrict__ wfrag,  // B-fragments bf16
    const float* __restrict__ bias,
    float* __restrict__ out)                   // NHWC fp32 (pre-relu)
{
    constexpr int KS = IC / 32;
    constexpr int NT = OC / 16;
    constexpr int NG = NT / NL;                // wave-groups per strip
    constexpr int NSTRIPS = NB * OH * OW / 16;

    const int wid  = (blockIdx.x * 256 + threadIdx.x) >> 6;
    const int lane = threadIdx.x & 63;
    const int ntb  = (wid % NG) * NL;
    const int s    = wid / NG;
    if (s >= NSTRIPS) return;
    const int quad = lane >> 4;
    const int lm   = lane & 15;

    const int p0 = s * 16;
    const int posA = p0 + lm;
    const int b  = posA / (OH * OW);
    const int rr = posA % (OH * OW);
    const int oy = rr / OW, ox = rr % OW;
    const int iy0 = oy * 2 - 1, ix0 = ox * 2 - 1;

    int cell[9];
    bool okb[9];
    #pragma unroll
    for (int t9 = 0; t9 < 9; t9++) {
        const int iy = iy0 + t9 / 3;
        const int ix = ix0 + t9 % 3;
        const bool ok = (iy >= 0) && (iy < IH) && (ix >= 0) && (ix < IW);
        cell[t9] = ok ? ((b * IH + iy) * IW + ix) : 0;   // clamp addr, not load
        okb[t9] = ok;
    }

    short8 zero8;
    #pragma unroll
    for (int j = 0; j < 8; j++) zero8[j] = 0;

    f32x4 acc[NL][2];
    #pragma unroll
    for (int nl = 0; nl < NL; nl++)
        #pragma unroll
        for (int pp = 0; pp < 2; pp++)
            acc[nl][pp] = (f32x4){0.f, 0.f, 0.f, 0.f};

    #pragma unroll 1
    for (int ks = 0; ks < KS; ks++) {
        short8 av[9];
        #pragma unroll
        for (int t9 = 0; t9 < 9; t9++) {
            short8 v = *(const short8*)(inPtr + (long)cell[t9] * IC + ks * 32 + quad * 8);
            av[t9] = okb[t9] ? v : zero8;      // reg-reg cndmask
        }
        #pragma unroll
        for (int nl = 0; nl < NL; nl++) {
            #pragma unroll
            for (int t9 = 0; t9 < 9; t9++) {
                short8 bf = *(const short8*)(wfrag + (((t9 * KS + ks) * NT + ntb + nl) * 64 + lane) * 8);
                if (t9 & 1) acc[nl][1] = __builtin_amdgcn_mfma_f32_16x16x32_bf16(av[t9], bf, acc[nl][1], 0, 0, 0);
                else        acc[nl][0] = __builtin_amdgcn_mfma_f32_16x16x32_bf16(av[t9], bf, acc[nl][0], 0, 0, 0);
            }
        }
    }

    const long rowBase = (long)p0 + quad * 4;   // D: row=(lane>>4)*4+reg
    #pragma unroll
    for (int nl = 0; nl < NL; nl++) {
        const int oc = (ntb + nl) * 16 + lm;
        const float bv = bias[oc];
        #pragma unroll
        for (int reg = 0; reg < 4; reg++)
            out[(rowBase + reg) * OC + oc] = acc[nl][0][reg] + acc[nl][1][reg] + bv;
    }
}

// ---------------------------------------------------------------------------
// 3x3 stride-1 pad-1 maxpool (-inf pad) + ReLU, NHWC. fp32 in; bf16 or fp32
// out (bf16 feeds the next conv's MFMA A-operand).
// ---------------------------------------------------------------------------
template<int C, int HH, int WW, bool BF16OUT>
__global__ __launch_bounds__(256) void maxpool3_relu(const float* __restrict__ in, void* __restrict__ outv) {
    constexpr int C4 = C / 4;
    int i = blockIdx.x * blockDim.x + threadIdx.x;
    if (i >= NB * HH * WW * C4) return;
    int c = i % C4;
    int x = (i / C4) % WW;
    int y = (i / (C4 * WW)) % HH;
    int b = i / (C4 * WW * HH);
    float4 m = make_float4(-3.0e38f, -3.0e38f, -3.0e38f, -3.0e38f);
    #pragma unroll
    for (int dy = -1; dy <= 1; dy++) {
        int yy = y + dy;
        if (yy < 0 || yy >= HH) continue;
        #pragma unroll
        for (int dx = -1; dx <= 1; dx++) {
            int xx = x + dx;
            if (xx < 0 || xx >= WW) continue;
            float4 v = ((const float4*)in)[((b * HH + yy) * WW + xx) * C4 + c];
            m.x = fmaxf(m.x, v.x);
            m.y = fmaxf(m.y, v.y);
            m.z = fmaxf(m.z, v.z);
            m.w = fmaxf(m.w, v.w);
        }
    }
    m.x = fmaxf(m.x, 0.f);
    m.y = fmaxf(m.y, 0.f);
    m.z = fmaxf(m.z, 0.f);
    m.w = fmaxf(m.w, 0.f);
    if (BF16OUT) {
        ushort4 o;
        o.x = f2bf(m.x); o.y = f2bf(m.y); o.z = f2bf(m.z); o.w = f2bf(m.w);
        ((ushort4*)outv)[i] = o;
    } else {
        ((float4*)outv)[i] = m;
    }
}

// ---------------------------------------------------------------------------
// LDS-tiled permute: in[b][pos][c] (NHWC pooled3 fp32, pos=480,c=128) ->
// xT[c*480+pos][b]. Both sides coalesced float4.
// ---------------------------------------------------------------------------
__global__ __launch_bounds__(256) void transpose_fc(const float* __restrict__ in, float* __restrict__ xT) {
    __shared__ float tile_s[32 * 16 * 17];    // [c_l][pos_l][b(pad 17)]
    const int pt = blockIdx.x % 30;
    const int ct = blockIdx.x / 30;
    const int pos0 = pt * 16, c0 = ct * 32;
    const int t = threadIdx.x;
    {
        const int b = t / 16, pl = t % 16;
        const float4* src = (const float4*)(in + ((long)(b * 480 + pos0 + pl)) * 128 + c0);
        #pragma unroll
        for (int q = 0; q < 8; q++) {
            float4 v = src[q];
            tile_s[((4 * q + 0) * 16 + pl) * 17 + b] = v.x;
            tile_s[((4 * q + 1) * 16 + pl) * 17 + b] = v.y;
            tile_s[((4 * q + 2) * 16 + pl) * 17 + b] = v.z;
            tile_s[((4 * q + 3) * 16 + pl) * 17 + b] = v.w;
        }
    }
    __syncthreads();
    {
        const int w = t / 64, l = t % 64;
        const int pl2 = l / 4, b4 = l % 4;
        #pragma unroll
        for (int i = 0; i < 8; i++) {
            int cl = w + 4 * i;
            const float* ls = &tile_s[(cl * 16 + pl2) * 17 + 4 * b4];
            float4 v = make_float4(ls[0], ls[1], ls[2], ls[3]);
            *(float4*)(xT + ((long)(c0 + cl) * 480 + pos0 + pl2) * 16 + 4 * b4) = v;
        }
    }
}

// ---------------------------------------------------------------------------
// FC stage 1 (fp32, exact weights): 64 oc-tiles x 30 k-chunks (KC=2048) =
// 1920 blocks. Each thread owns 4 CONSECUTIVE k per step -> fw loads are
// float4 (1 KB/wave contiguous per oc-row): R11 showed scalar 4-B fw loads
// capped the 63 MB stream at 1.56 TB/s (request-rate bound, 40 us).
// acc indices ALL compile-time (R4 lesson: dynamic index -> scratch spill).
// ---------------------------------------------------------------------------
__global__ __launch_bounds__(256) void fc_stage1(const float* __restrict__ xT,
                                                 const float* __restrict__ fw,
                                                 float* __restrict__ partial)
{
    __shared__ float red[32 * 257];
    const int tile  = blockIdx.x / 30;
    const int chunk = blockIdx.x % 30;
    const int t = threadIdx.x;
    const int K = 61440, KC = 2048;

    float acc[4][16];
    #pragma unroll
    for (int o = 0; o < 4; o++)
        #pragma unroll
        for (int bb = 0; bb < 16; bb++) acc[o][bb] = 0.f;

    const int kBase = chunk * KC + t * 4;
    #pragma unroll 1
    for (int it = 0; it < 2; it++) {        // KC / (256 thr * 4 k) = 2
        const int k = kBase + it * 1024;
        float4 w0 = *(const float4*)&fw[(long)(tile * 4 + 0) * K + k];
        float4 w1 = *(const float4*)&fw[(long)(tile * 4 + 1) * K + k];
        float4 w2 = *(const float4*)&fw[(long)(tile * 4 + 2) * K + k];
        float4 w3 = *(const float4*)&fw[(long)(tile * 4 + 3) * K + k];
        #pragma unroll
        for (int dk = 0; dk < 4; dk++) {
            const float4* xp = (const float4*)(xT + (long)(k + dk) * 16);
            float4 x0 = xp[0], x1 = xp[1], x2 = xp[2], x3 = xp[3];
            const float wv0 = (dk == 0) ? w0.x : (dk == 1) ? w0.y : (dk == 2) ? w0.z : w0.w;
            const float wv1 = (dk == 0) ? w1.x : (dk == 1) ? w1.y : (dk == 2) ? w1.z : w1.w;
            const float wv2 = (dk == 0) ? w2.x : (dk == 1) ? w2.y : (dk == 2) ? w2.z : w2.w;
            const float wv3 = (dk == 0) ? w3.x : (dk == 1) ? w3.y : (dk == 2) ? w3.z : w3.w;
            acc[0][0]  = fmaf(wv0, x0.x, acc[0][0]);  acc[0][1]  = fmaf(wv0, x0.y, acc[0][1]);
            acc[0][2]  = fmaf(wv0, x0.z, acc[0][2]);  acc[0][3]  = fmaf(wv0, x0.w, acc[0][3]);
            acc[0][4]  = fmaf(wv0, x1.x, acc[0][4]);  acc[0][5]  = fmaf(wv0, x1.y, acc[0][5]);
            acc[0][6]  = fmaf(wv0, x1.z, acc[0][6]);  acc[0][7]  = fmaf(wv0, x1.w, acc[0][7]);
            acc[0][8]  = fmaf(wv0, x2.x, acc[0][8]);  acc[0][9]  = fmaf(wv0, x2.y, acc[0][9]);
            acc[0][10] = fmaf(wv0, x2.z, acc[0][10]); acc[0][11] = fmaf(wv0, x2.w, acc[0][11]);
            acc[0][12] = fmaf(wv0, x3.x, acc[0][12]); acc[0][13] = fmaf(wv0, x3.y, acc[0][13]);
            acc[0][14] = fmaf(wv0, x3.z, acc[0][14]); acc[0][15] = fmaf(wv0, x3.w, acc[0][15]);
            acc[1][0]  = fmaf(wv1, x0.x, acc[1][0]);  acc[1][1]  = fmaf(wv1, x0.y, acc[1][1]);
            acc[1][2]  = fmaf(wv1, x0.z, acc[1][2]);  acc[1][3]  = fmaf(wv1, x0.w, acc[1][3]);
            acc[1][4]  = fmaf(wv1, x1.x, acc[1][4]);  acc[1][5]  = fmaf(wv1, x1.y, acc[1][5]);
            acc[1][6]  = fmaf(wv1, x1.z, acc[1][6]);  acc[1][7]  = fmaf(wv1, x1.w, acc[1][7]);
            acc[1][8]  = fmaf(wv1, x2.x, acc[1][8]);  acc[1][9]  = fmaf(wv1, x2.y, acc[1][9]);
            acc[1][10] = fmaf(wv1, x2.z, acc[1][10]); acc[1][11] = fmaf(wv1, x2.w, acc[1][11]);
            acc[1][12] = fmaf(wv1, x3.x, acc[1][12]); acc[1][13] = fmaf(wv1, x3.y, acc[1][13]);
            acc[1][14] = fmaf(wv1, x3.z, acc[1][14]); acc[1][15] = fmaf(wv1, x3.w, acc[1][15]);
            acc[2][0]  = fmaf(wv2, x0.x, acc[2][0]);  acc[2][1]  = fmaf(wv2, x0.y, acc[2][1]);
            acc[2][2]  = fmaf(wv2, x0.z, acc[2][2]);  acc[2][3]  = fmaf(wv2, x0.w, acc[2][3]);
            acc[2][4]  = fmaf(wv2, x1.x, acc[2][4]);  acc[2][5]  = fmaf(wv2, x1.y, acc[2][5]);
            acc[2][6]  = fmaf(wv2, x1.z, acc[2][6]);  acc[2][7]  = fmaf(wv2, x1.w, acc[2][7]);
            acc[2][8]  = fmaf(wv2, x2.x, acc[2][8]);  acc[2][9]  = fmaf(wv2, x2.y, acc[2][9]);
            acc[2][10] = fmaf(wv2, x2.z, acc[2][10]); acc[2][11] = fmaf(wv2, x2.w, acc[2][11]);
            acc[2][12] = fmaf(wv2, x3.x, acc[2][12]); acc[2][13] = fmaf(wv2, x3.y, acc[2][13]);
            acc[2][14] = fmaf(wv2, x3.z, acc[2][14]); acc[2][15] = fmaf(wv2, x3.w, acc[2][15]);
            acc[3][0]  = fmaf(wv3, x0.x, acc[3][0]);  acc[3][1]  = fmaf(wv3, x0.y, acc[3][1]);
            acc[3][2]  = fmaf(wv3, x0.z, acc[3][2]);  acc[3][3]  = fmaf(wv3, x0.w, acc[3][3]);
            acc[3][4]  = fmaf(wv3, x1.x, acc[3][4]);  acc[3][5]  = fmaf(wv3, x1.y, acc[3][5]);
            acc[3][6]  = fmaf(wv3, x1.z, acc[3][6]);  acc[3][7]  = fmaf(wv3, x1.w, acc[3][7]);
            acc[3][8]  = fmaf(wv3, x2.x, acc[3][8]);  acc[3][9]  = fmaf(wv3, x2.y, acc[3][9]);
            acc[3][10] = fmaf(wv3, x2.z, acc[3][10]); acc[3][11] = fmaf(wv3, x2.w, acc[3][11]);
            acc[3][12] = fmaf(wv3, x3.x, acc[3][12]); acc[3][13] = fmaf(wv3, x3.y, acc[3][13]);
            acc[3][14] = fmaf(wv3, x3.z, acc[3][14]); acc[3][15] = fmaf(wv3, x3.w, acc[3][15]);
        }
    }

    // phase 0: acc[0], acc[1]
    #pragma unroll
    for (int oo = 0; oo < 2; oo++)
        #pragma unroll
        for (int bb = 0; bb < 16; bb++)
            red[(oo * 16 + bb) * 257 + t] = acc[oo][bb];
    __syncthreads();
    if (t < 32) {
        float s = 0.f;
        for (int i = 0; i < 256; i++) s += red[t * 257 + i];
        partial[((long)chunk * 256 + tile * 4 + (t / 16)) * 16 + (t % 16)] = s;
    }
    __syncthreads();
    // phase 1: acc[2], acc[3]
    #pragma unroll
    for (int oo = 0; oo < 2; oo++)
        #pragma unroll
        for (int bb = 0; bb < 16; bb++)
            red[(oo * 16 + bb) * 257 + t] = acc[2 + oo][bb];
    __syncthreads();
    if (t < 32) {
        float s = 0.f;
        for (int i = 0; i < 256; i++) s += red[t * 257 + i];
        partial[((long)chunk * 256 + tile * 4 + 2 + (t / 16)) * 16 + (t % 16)] = s;
    }
}

__global__ __launch_bounds__(256) void fc_reduce(const float* __restrict__ partial,
                                                 const float* __restrict__ fcb,
                                                 float* __restrict__ out)
{
    int i = blockIdx.x * blockDim.x + threadIdx.x;   // 4096
    if (i >= 4096) return;
    int oc = i / 16, b = i % 16;
    float s = fcb[oc];
    #pragma unroll
    for (int c = 0; c < 30; c++) s += partial[(c * 256 + oc) * 16 + b];
    out[b * 256 + oc] = fmaxf(s, 0.f);
}

// ---------------------------------------------------------------------------
extern "C" void kernel_launch(void* const* d_in, const int* in_sizes, int n_in,
                              void* d_out, int out_size, void* d_ws, size_t ws_size,
                              hipStream_t stream) {
    const float* input  = (const float*)d_in[0];
    const int*   coords = (const int*)d_in[1];
    const float* w1 = (const float*)d_in[2];
    const float* b1 = (const float*)d_in[3];
    const float* w2 = (const float*)d_in[4];
    const float* b2 = (const float*)d_in[5];
    const float* w3 = (const float*)d_in[6];
    const float* b3 = (const float*)d_in[7];
    const float* fcw = (const float*)d_in[8];
    const float* fcb = (const float*)d_in[9];
    float* outp = (float*)d_out;

    const int n_active = in_sizes[1] / 3;

    // ---- workspace layout (~56 MB total) ----
    char* ws = (char*)d_ws;
    unsigned short* wf1 = (unsigned short*)ws;            // 18,432 B
    unsigned short* wf2 = wf1 + 9216;                     // 36,864 B
    unsigned short* wf3 = wf2 + 18432;                    // 147,456 B
    unsigned short* inBf = (unsigned short*)(ws + 204800);        // 31,457,280 B (16*96*320*32 bf16)
    char* regA = ws + 204800 + 31457280;                  // 15,728,640 B
    char* regB = regA + 15728640;                         // 7,864,320 B
    float* partial = (float*)(regB + 7864320);            // 491,520 B (30*256*16 fp32)

    // ping-pong aliasing (stream-ordered, each buffer dead before reuse):
    float*          conv1o  = (float*)regA;           // 15.73 MB fp32
    unsigned short* pool1bf = (unsigned short*)regB;   //  7.86 MB bf16
    float*          conv2o  = (float*)regA;           //  7.86 MB fp32
    unsigned short* pool2bf = (unsigned short*)regB;   //  3.93 MB bf16
    float*          conv3o  = (float*)regA;           //  3.93 MB fp32
    float*          pool3f  = (float*)regB;           //  3.93 MB fp32
    float*          xT      = (float*)regA;           //  3.93 MB fp32

    // zero dense bf16 input (31,457,280 B), then fused wfrag-prep +
    // scatter-cast of active cells only.
    hipMemsetAsync(inBf, 0, 31457280, stream);
    const int scatterBlocks = (n_active * 4 + 255) / 256;
    setup_all<<<396 + scatterBlocks, 256, 0, stream>>>(w1, w2, w3, wf1, wf2, wf3,
                                                       coords, input, inBf, n_active);

    // conv1: (16,96,320,32)->(16,48,160,32); NT=2 NL=2 -> 7680 waves
    conv_mfma<32, 32, 2, 96, 320, 48, 160>
        <<<1920, 256, 0, stream>>>(inBf, wf1, b1, conv1o);
    maxpool3_relu<32, 48, 160, true><<<3840, 256, 0, stream>>>(conv1o, pool1bf);

    // conv2: (16,48,160,32)->(16,24,80,64); NT=4 NL=2 -> 3840 waves
    conv_mfma<32, 64, 2, 48, 160, 24, 80>
        <<<960, 256, 0, stream>>>(pool1bf, wf2, b2, conv2o);
    maxpool3_relu<64, 24, 80, true><<<1920, 256, 0, stream>>>(conv2o, pool2bf);

    // conv3: (16,24,80,64)->(16,12,40,128); NT=8 NL=2 -> 1920 waves
    conv_mfma<64, 128, 2, 24, 80, 12, 40>
        <<<480, 256, 0, stream>>>(pool2bf, wf3, b3, conv3o);
    maxpool3_relu<128, 12, 40, false><<<960, 256, 0, stream>>>(conv3o, pool3f);

    // flatten permute + FC (fp32, exact weights)
    transpose_fc<<<120, 256, 0, stream>>>(pool3f, xT);
    fc_stage1<<<1920, 256, 0, stream>>>(xT, fcw, partial);
    fc_reduce<<<16, 256, 0, stream>>>(partial, fcb, outp);
}

// Round 13
// 262.440 us; speedup vs baseline: 1.0387x; 1.0387x over previous
//
#include <hip/hip_runtime.h>

// Problem constants
#define NB 16
#define NH 96
#define NW 320
#define NCIN 32

typedef __attribute__((ext_vector_type(8))) short short8;     // 8 bf16 (4 VGPRs)
typedef __attribute__((ext_vector_type(4))) float f32x4;

__device__ inline unsigned short f2bf(float f) {
    union { float f; unsigned int u; } v; v.f = f;
    unsigned int r = v.u + 0x7FFF + ((v.u >> 16) & 1);   // RNE
    return (unsigned short)(r >> 16);
}

// ---------------------------------------------------------------------------
// Fused setup kernel.
// Blocks [0,396): weight fragments OIHW fp32 -> MFMA B-operand bf16,
//   wf[((kk*NT + nt)*64 + lane)*8 + j], oc = nt*16+(lane&15),
//   ic = ks*32+(lane>>4)*8+j  [m91-verified map]
// Blocks [396,...): scatter+cast active cells from fp32 input into the
//   (memset-zeroed) dense bf16 input. Reads ONLY active cells (~25.6 MB).
// ---------------------------------------------------------------------------
__global__ __launch_bounds__(256) void setup_all(const float* __restrict__ w1,
                                                 const float* __restrict__ w2,
                                                 const float* __restrict__ w3,
                                                 unsigned short* __restrict__ f1,
                                                 unsigned short* __restrict__ f2,
                                                 unsigned short* __restrict__ f3,
                                                 const int* __restrict__ coords,
                                                 const float* __restrict__ input,
                                                 unsigned short* __restrict__ inBf,
                                                 int n) {
    if (blockIdx.x < 396) {
        int i = blockIdx.x * 256 + threadIdx.x;
        if (i < 9216) {                       // conv1: IC=32 OC=32 NT=2 KS=1
            int j = i & 7, lane = (i >> 3) & 63, nt = (i >> 9) & 1, tap = i >> 10;
            int ic = ((lane >> 4) * 8) + j, oc = nt * 16 + (lane & 15);
            f1[i] = f2bf(w1[(oc * 32 + ic) * 9 + tap]);
        } else if (i < 27648) {               // conv2: IC=32 OC=64 NT=4 KS=1
            int v = i - 9216;
            int j = v & 7, lane = (v >> 3) & 63, nt = (v >> 9) & 3, tap = v >> 11;
            int ic = ((lane >> 4) * 8) + j, oc = nt * 16 + (lane & 15);
            f2[v] = f2bf(w2[(oc * 32 + ic) * 9 + tap]);
        } else if (i < 101376) {              // conv3: IC=64 OC=128 NT=8 KS=2
            int v = i - 27648;
            int j = v & 7, lane = (v >> 3) & 63, nt = (v >> 9) & 7, kk = v >> 12;
            int tap = kk >> 1, ks = kk & 1;
            int ic = ks * 32 + ((lane >> 4) * 8) + j, oc = nt * 16 + (lane & 15);
            f3[v] = f2bf(w3[(oc * 64 + ic) * 9 + tap]);
        }
    } else {
        int i = (blockIdx.x - 396) * 256 + threadIdx.x;
        if (i >= n * 4) return;
        int ci = i >> 2, q = i & 3;
        int b = coords[ci * 3 + 0], y = coords[ci * 3 + 1], x = coords[ci * 3 + 2];
        long base = ((long)((b * NH + y) * NW + x)) * NCIN + q * 8;
        const float4* src = (const float4*)(input + base);
        float4 v0 = src[0], v1 = src[1];
        union { short8 s8; unsigned short us[8]; } o;
        o.us[0] = f2bf(v0.x); o.us[1] = f2bf(v0.y); o.us[2] = f2bf(v0.z); o.us[3] = f2bf(v0.w);
        o.us[4] = f2bf(v1.x); o.us[5] = f2bf(v1.y); o.us[6] = f2bf(v1.z); o.us[7] = f2bf(v1.w);
        *(short8*)(inBf + base) = o.s8;
    }
}

// ---------------------------------------------------------------------------
// Implicit-GEMM conv 3x3 stride-2 pad-1 via bf16 MFMA (16x16x32), bf16 NHWC in.
// Each wave: one 16-position strip x NL oc-tiles. A-fragments loaded ONCE
// per ks, reused for NL*9 MFMAs. Unconditional loads, addr clamped, reg-reg
// cndmask (R8). acc indices compile-time (R4); ks loop unroll 1 (R2).
// Layouts m89/m91.
// ---------------------------------------------------------------------------
template<int IC, int OC, int NL, int IH, int IW, int OH, int OW>
__global__ __launch_bounds__(256) void conv_mfma(
    const unsigned short* __restrict__ inPtr,  // NHWC bf16
    const unsigned short* __restrict__ wfrag,  // B-fragments bf16
    const float* __restrict__ bias,
    float* __restrict__ out)                   // NHWC fp32 (pre-relu)
{
    constexpr int KS = IC / 32;
    constexpr int NT = OC / 16;
    constexpr int NG = NT / NL;                // wave-groups per strip
    constexpr int NSTRIPS = NB * OH * OW / 16;

    const int wid  = (blockIdx.x * 256 + threadIdx.x) >> 6;
    const int lane = threadIdx.x & 63;
    const int ntb  = (wid % NG) * NL;
    const int s    = wid / NG;
    if (s >= NSTRIPS) return;
    const int quad = lane >> 4;
    const int lm   = lane & 15;

    const int p0 = s * 16;
    const int posA = p0 + lm;
    const int b  = posA / (OH * OW);
    const int rr = posA % (OH * OW);
    const int oy = rr / OW, ox = rr % OW;
    const int iy0 = oy * 2 - 1, ix0 = ox * 2 - 1;

    int cell[9];
    bool okb[9];
    #pragma unroll
    for (int t9 = 0; t9 < 9; t9++) {
        const int iy = iy0 + t9 / 3;
        const int ix = ix0 + t9 % 3;
        const bool ok = (iy >= 0) && (iy < IH) && (ix >= 0) && (ix < IW);
        cell[t9] = ok ? ((b * IH + iy) * IW + ix) : 0;   // clamp addr, not load
        okb[t9] = ok;
    }

    short8 zero8;
    #pragma unroll
    for (int j = 0; j < 8; j++) zero8[j] = 0;

    f32x4 acc[NL][2];
    #pragma unroll
    for (int nl = 0; nl < NL; nl++)
        #pragma unroll
        for (int pp = 0; pp < 2; pp++)
            acc[nl][pp] = (f32x4){0.f, 0.f, 0.f, 0.f};

    #pragma unroll 1
    for (int ks = 0; ks < KS; ks++) {
        short8 av[9];
        #pragma unroll
        for (int t9 = 0; t9 < 9; t9++) {
            short8 v = *(const short8*)(inPtr + (long)cell[t9] * IC + ks * 32 + quad * 8);
            av[t9] = okb[t9] ? v : zero8;      // reg-reg cndmask
        }
        #pragma unroll
        for (int nl = 0; nl < NL; nl++) {
            #pragma unroll
            for (int t9 = 0; t9 < 9; t9++) {
                short8 bf = *(const short8*)(wfrag + (((t9 * KS + ks) * NT + ntb + nl) * 64 + lane) * 8);
                if (t9 & 1) acc[nl][1] = __builtin_amdgcn_mfma_f32_16x16x32_bf16(av[t9], bf, acc[nl][1], 0, 0, 0);
                else        acc[nl][0] = __builtin_amdgcn_mfma_f32_16x16x32_bf16(av[t9], bf, acc[nl][0], 0, 0, 0);
            }
        }
    }

    const long rowBase = (long)p0 + quad * 4;   // D: row=(lane>>4)*4+reg
    #pragma unroll
    for (int nl = 0; nl < NL; nl++) {
        const int oc = (ntb + nl) * 16 + lm;
        const float bv = bias[oc];
        #pragma unroll
        for (int reg = 0; reg < 4; reg++)
            out[(rowBase + reg) * OC + oc] = acc[nl][0][reg] + acc[nl][1][reg] + bv;
    }
}

// ---------------------------------------------------------------------------
// 3x3 stride-1 pad-1 maxpool (-inf pad) + ReLU, NHWC. fp32 in; bf16 or fp32 out.
// ---------------------------------------------------------------------------
template<int C, int HH, int WW, bool BF16OUT>
__global__ __launch_bounds__(256) void maxpool3_relu(const float* __restrict__ in, void* __restrict__ outv) {
    constexpr int C4 = C / 4;
    int i = blockIdx.x * blockDim.x + threadIdx.x;
    if (i >= NB * HH * WW * C4) return;
    int c = i % C4;
    int x = (i / C4) % WW;
    int y = (i / (C4 * WW)) % HH;
    int b = i / (C4 * WW * HH);
    float4 m = make_float4(-3.0e38f, -3.0e38f, -3.0e38f, -3.0e38f);
    #pragma unroll
    for (int dy = -1; dy <= 1; dy++) {
        int yy = y + dy;
        if (yy < 0 || yy >= HH) continue;
        #pragma unroll
        for (int dx = -1; dx <= 1; dx++) {
            int xx = x + dx;
            if (xx < 0 || xx >= WW) continue;
            float4 v = ((const float4*)in)[((b * HH + yy) * WW + xx) * C4 + c];
            m.x = fmaxf(m.x, v.x);
            m.y = fmaxf(m.y, v.y);
            m.z = fmaxf(m.z, v.z);
            m.w = fmaxf(m.w, v.w);
        }
    }
    m.x = fmaxf(m.x, 0.f);
    m.y = fmaxf(m.y, 0.f);
    m.z = fmaxf(m.z, 0.f);
    m.w = fmaxf(m.w, 0.f);
    if (BF16OUT) {
        ushort4 o;
        o.x = f2bf(m.x); o.y = f2bf(m.y); o.z = f2bf(m.z); o.w = f2bf(m.w);
        ((ushort4*)outv)[i] = o;
    } else {
        ((float4*)outv)[i] = m;
    }
}

// ---------------------------------------------------------------------------
// LDS-tiled permute: in[b][pos][c] (NHWC pooled3 fp32, pos=480,c=128) ->
// xT[c*480+pos][b]. Both sides coalesced float4.
// ---------------------------------------------------------------------------
__global__ __launch_bounds__(256) void transpose_fc(const float* __restrict__ in, float* __restrict__ xT) {
    __shared__ float tile_s[32 * 16 * 17];    // [c_l][pos_l][b(pad 17)]
    const int pt = blockIdx.x % 30;
    const int ct = blockIdx.x / 30;
    const int pos0 = pt * 16, c0 = ct * 32;
    const int t = threadIdx.x;
    {
        const int b = t / 16, pl = t % 16;
        const float4* src = (const float4*)(in + ((long)(b * 480 + pos0 + pl)) * 128 + c0);
        #pragma unroll
        for (int q = 0; q < 8; q++) {
            float4 v = src[q];
            tile_s[((4 * q + 0) * 16 + pl) * 17 + b] = v.x;
            tile_s[((4 * q + 1) * 16 + pl) * 17 + b] = v.y;
            tile_s[((4 * q + 2) * 16 + pl) * 17 + b] = v.z;
            tile_s[((4 * q + 3) * 16 + pl) * 17 + b] = v.w;
        }
    }
    __syncthreads();
    {
        const int w = t / 64, l = t % 64;
        const int pl2 = l / 4, b4 = l % 4;
        #pragma unroll
        for (int i = 0; i < 8; i++) {
            int cl = w + 4 * i;
            const float* ls = &tile_s[(cl * 16 + pl2) * 17 + 4 * b4];
            float4 v = make_float4(ls[0], ls[1], ls[2], ls[3]);
            *(float4*)(xT + ((long)(c0 + cl) * 480 + pos0 + pl2) * 16 + 4 * b4) = v;
        }
    }
}

// ---------------------------------------------------------------------------
// FC stage 1: 64 oc-tiles x 15 k-chunks (KC=4096) = 960 blocks. Each thread
// owns 4 consecutive k -> float4 fw loads (R12's load-path fix, kept).
// Epilogue: 6-step __shfl_xor butterfly over the 64 lanes for all 64 acc
// elements (compile-time indices), lane0/wave writes 64 sums to 1 KB LDS,
// threads 0..63 fold 4 waves. R12 post-mortem: the 32x257 LDS dump +
// 32-thread serial 256-sum epilogue was the regression (constant per block,
// amortization halved when KC halved). LDS 33 KB -> 1 KB also lifts the
// 4-blocks/CU LDS cap.
// ---------------------------------------------------------------------------
__global__ __launch_bounds__(256) void fc_stage1(const float* __restrict__ xT,
                                                 const float* __restrict__ fw,
                                                 float* __restrict__ partial)
{
    __shared__ float red[4 * 64];              // [wave][element]
    const int tile  = blockIdx.x / 15;
    const int chunk = blockIdx.x % 15;
    const int t = threadIdx.x;
    const int wave = t >> 6;
    const int lane = t & 63;
    const int K = 61440, KC = 4096;

    float acc[4][16];
    #pragma unroll
    for (int o = 0; o < 4; o++)
        #pragma unroll
        for (int bb = 0; bb < 16; bb++) acc[o][bb] = 0.f;

    const int kBase = chunk * KC + t * 4;
    #pragma unroll 1
    for (int it = 0; it < 4; it++) {        // KC / (256 thr * 4 k) = 4
        const int k = kBase + it * 1024;
        float4 w0 = *(const float4*)&fw[(long)(tile * 4 + 0) * K + k];
        float4 w1 = *(const float4*)&fw[(long)(tile * 4 + 1) * K + k];
        float4 w2 = *(const float4*)&fw[(long)(tile * 4 + 2) * K + k];
        float4 w3 = *(const float4*)&fw[(long)(tile * 4 + 3) * K + k];
        #pragma unroll
        for (int dk = 0; dk < 4; dk++) {
            const float4* xp = (const float4*)(xT + (long)(k + dk) * 16);
            float4 x0 = xp[0], x1 = xp[1], x2 = xp[2], x3 = xp[3];
            const float wv0 = (dk == 0) ? w0.x : (dk == 1) ? w0.y : (dk == 2) ? w0.z : w0.w;
            const float wv1 = (dk == 0) ? w1.x : (dk == 1) ? w1.y : (dk == 2) ? w1.z : w1.w;
            const float wv2 = (dk == 0) ? w2.x : (dk == 1) ? w2.y : (dk == 2) ? w2.z : w2.w;
            const float wv3 = (dk == 0) ? w3.x : (dk == 1) ? w3.y : (dk == 2) ? w3.z : w3.w;
            acc[0][0]  = fmaf(wv0, x0.x, acc[0][0]);  acc[0][1]  = fmaf(wv0, x0.y, acc[0][1]);
            acc[0][2]  = fmaf(wv0, x0.z, acc[0][2]);  acc[0][3]  = fmaf(wv0, x0.w, acc[0][3]);
            acc[0][4]  = fmaf(wv0, x1.x, acc[0][4]);  acc[0][5]  = fmaf(wv0, x1.y, acc[0][5]);
            acc[0][6]  = fmaf(wv0, x1.z, acc[0][6]);  acc[0][7]  = fmaf(wv0, x1.w, acc[0][7]);
            acc[0][8]  = fmaf(wv0, x2.x, acc[0][8]);  acc[0][9]  = fmaf(wv0, x2.y, acc[0][9]);
            acc[0][10] = fmaf(wv0, x2.z, acc[0][10]); acc[0][11] = fmaf(wv0, x2.w, acc[0][11]);
            acc[0][12] = fmaf(wv0, x3.x, acc[0][12]); acc[0][13] = fmaf(wv0, x3.y, acc[0][13]);
            acc[0][14] = fmaf(wv0, x3.z, acc[0][14]); acc[0][15] = fmaf(wv0, x3.w, acc[0][15]);
            acc[1][0]  = fmaf(wv1, x0.x, acc[1][0]);  acc[1][1]  = fmaf(wv1, x0.y, acc[1][1]);
            acc[1][2]  = fmaf(wv1, x0.z, acc[1][2]);  acc[1][3]  = fmaf(wv1, x0.w, acc[1][3]);
            acc[1][4]  = fmaf(wv1, x1.x, acc[1][4]);  acc[1][5]  = fmaf(wv1, x1.y, acc[1][5]);
            acc[1][6]  = fmaf(wv1, x1.z, acc[1][6]);  acc[1][7]  = fmaf(wv1, x1.w, acc[1][7]);
            acc[1][8]  = fmaf(wv1, x2.x, acc[1][8]);  acc[1][9]  = fmaf(wv1, x2.y, acc[1][9]);
            acc[1][10] = fmaf(wv1, x2.z, acc[1][10]); acc[1][11] = fmaf(wv1, x2.w, acc[1][11]);
            acc[1][12] = fmaf(wv1, x3.x, acc[1][12]); acc[1][13] = fmaf(wv1, x3.y, acc[1][13]);
            acc[1][14] = fmaf(wv1, x3.z, acc[1][14]); acc[1][15] = fmaf(wv1, x3.w, acc[1][15]);
            acc[2][0]  = fmaf(wv2, x0.x, acc[2][0]);  acc[2][1]  = fmaf(wv2, x0.y, acc[2][1]);
            acc[2][2]  = fmaf(wv2, x0.z, acc[2][2]);  acc[2][3]  = fmaf(wv2, x0.w, acc[2][3]);
            acc[2][4]  = fmaf(wv2, x1.x, acc[2][4]);  acc[2][5]  = fmaf(wv2, x1.y, acc[2][5]);
            acc[2][6]  = fmaf(wv2, x1.z, acc[2][6]);  acc[2][7]  = fmaf(wv2, x1.w, acc[2][7]);
            acc[2][8]  = fmaf(wv2, x2.x, acc[2][8]);  acc[2][9]  = fmaf(wv2, x2.y, acc[2][9]);
            acc[2][10] = fmaf(wv2, x2.z, acc[2][10]); acc[2][11] = fmaf(wv2, x2.w, acc[2][11]);
            acc[2][12] = fmaf(wv2, x3.x, acc[2][12]); acc[2][13] = fmaf(wv2, x3.y, acc[2][13]);
            acc[2][14] = fmaf(wv2, x3.z, acc[2][14]); acc[2][15] = fmaf(wv2, x3.w, acc[2][15]);
            acc[3][0]  = fmaf(wv3, x0.x, acc[3][0]);  acc[3][1]  = fmaf(wv3, x0.y, acc[3][1]);
            acc[3][2]  = fmaf(wv3, x0.z, acc[3][2]);  acc[3][3]  = fmaf(wv3, x0.w, acc[3][3]);
            acc[3][4]  = fmaf(wv3, x1.x, acc[3][4]);  acc[3][5]  = fmaf(wv3, x1.y, acc[3][5]);
            acc[3][6]  = fmaf(wv3, x1.z, acc[3][6]);  acc[3][7]  = fmaf(wv3, x1.w, acc[3][7]);
            acc[3][8]  = fmaf(wv3, x2.x, acc[3][8]);  acc[3][9]  = fmaf(wv3, x2.y, acc[3][9]);
            acc[3][10] = fmaf(wv3, x2.z, acc[3][10]); acc[3][11] = fmaf(wv3, x2.w, acc[3][11]);
            acc[3][12] = fmaf(wv3, x3.x, acc[3][12]); acc[3][13] = fmaf(wv3, x3.y, acc[3][13]);
            acc[3][14] = fmaf(wv3, x3.z, acc[3][14]); acc[3][15] = fmaf(wv3, x3.w, acc[3][15]);
        }
    }

    // butterfly reduce each acc element over the 64 lanes (compile-time idx)
    #pragma unroll
    for (int o = 0; o < 4; o++)
        #pragma unroll
        for (int bb = 0; bb < 16; bb++) {
            float v = acc[o][bb];
            v += __shfl_xor(v, 1);
            v += __shfl_xor(v, 2);
            v += __shfl_xor(v, 4);
            v += __shfl_xor(v, 8);
            v += __shfl_xor(v, 16);
            v += __shfl_xor(v, 32);
            acc[o][bb] = v;
        }
    if (lane == 0) {
        #pragma unroll
        for (int o = 0; o < 4; o++)
            #pragma unroll
            for (int bb = 0; bb < 16; bb++)
                red[wave * 64 + o * 16 + bb] = acc[o][bb];
    }
    __syncthreads();
    if (t < 64) {
        float s = red[t] + red[64 + t] + red[128 + t] + red[192 + t];
        int o = t / 16, bb = t % 16;
        partial[((long)chunk * 256 + tile * 4 + o) * 16 + bb] = s;
    }
}

__global__ __launch_bounds__(256) void fc_reduce(const float* __restrict__ partial,
                                                 const float* __restrict__ fcb,
                                                 float* __restrict__ out)
{
    int i = blockIdx.x * blockDim.x + threadIdx.x;   // 4096
    if (i >= 4096) return;
    int oc = i / 16, b = i % 16;
    float s = fcb[oc];
    #pragma unroll
    for (int c = 0; c < 15; c++) s += partial[(c * 256 + oc) * 16 + b];
    out[b * 256 + oc] = fmaxf(s, 0.f);
}

// ---------------------------------------------------------------------------
extern "C" void kernel_launch(void* const* d_in, const int* in_sizes, int n_in,
                              void* d_out, int out_size, void* d_ws, size_t ws_size,
                              hipStream_t stream) {
    const float* input  = (const float*)d_in[0];
    const int*   coords = (const int*)d_in[1];
    const float* w1 = (const float*)d_in[2];
    const float* b1 = (const float*)d_in[3];
    const float* w2 = (const float*)d_in[4];
    const float* b2 = (const float*)d_in[5];
    const float* w3 = (const float*)d_in[6];
    const float* b3 = (const float*)d_in[7];
    const float* fcw = (const float*)d_in[8];
    const float* fcb = (const float*)d_in[9];
    float* outp = (float*)d_out;

    const int n_active = in_sizes[1] / 3;

    // ---- workspace layout (~56 MB total) ----
    char* ws = (char*)d_ws;
    unsigned short* wf1 = (unsigned short*)ws;            // 18,432 B
    unsigned short* wf2 = wf1 + 9216;                     // 36,864 B
    unsigned short* wf3 = wf2 + 18432;                    // 147,456 B
    unsigned short* inBf = (unsigned short*)(ws + 204800);        // 31,457,280 B (16*96*320*32 bf16)
    char* regA = ws + 204800 + 31457280;                  // 15,728,640 B
    char* regB = regA + 15728640;                         // 7,864,320 B
    float* partial = (float*)(regB + 7864320);            // 245,760 B (15*256*16 fp32)

    // ping-pong aliasing (stream-ordered, each buffer dead before reuse):
    float*          conv1o  = (float*)regA;           // 15.73 MB fp32
    unsigned short* pool1bf = (unsigned short*)regB;   //  7.86 MB bf16
    float*          conv2o  = (float*)regA;           //  7.86 MB fp32
    unsigned short* pool2bf = (unsigned short*)regB;   //  3.93 MB bf16
    float*          conv3o  = (float*)regA;           //  3.93 MB fp32
    float*          pool3f  = (float*)regB;           //  3.93 MB fp32
    float*          xT      = (float*)regA;           //  3.93 MB fp32

    // zero dense bf16 input, then fused wfrag-prep + scatter-cast.
    hipMemsetAsync(inBf, 0, 31457280, stream);
    const int scatterBlocks = (n_active * 4 + 255) / 256;
    setup_all<<<396 + scatterBlocks, 256, 0, stream>>>(w1, w2, w3, wf1, wf2, wf3,
                                                       coords, input, inBf, n_active);

    // conv1: (16,96,320,32)->(16,48,160,32); NT=2 NL=2 -> 7680 waves
    conv_mfma<32, 32, 2, 96, 320, 48, 160>
        <<<1920, 256, 0, stream>>>(inBf, wf1, b1, conv1o);
    maxpool3_relu<32, 48, 160, true><<<3840, 256, 0, stream>>>(conv1o, pool1bf);

    // conv2: (16,48,160,32)->(16,24,80,64); NT=4 NL=2 -> 3840 waves
    conv_mfma<32, 64, 2, 48, 160, 24, 80>
        <<<960, 256, 0, stream>>>(pool1bf, wf2, b2, conv2o);
    maxpool3_relu<64, 24, 80, true><<<1920, 256, 0, stream>>>(conv2o, pool2bf);

    // conv3: (16,24,80,64)->(16,12,40,128); NT=8 NL=2 -> 1920 waves
    conv_mfma<64, 128, 2, 24, 80, 12, 40>
        <<<480, 256, 0, stream>>>(pool2bf, wf3, b3, conv3o);
    maxpool3_relu<128, 12, 40, false><<<960, 256, 0, stream>>>(conv3o, pool3f);

    // flatten permute + FC (fp32, exact weights)
    transpose_fc<<<120, 256, 0, stream>>>(pool3f, xT);
    fc_stage1<<<960, 256, 0, stream>>>(xT, fcw, partial);
    fc_reduce<<<16, 256, 0, stream>>>(partial, fcb, outp);
}

// Round 14
// 254.916 us; speedup vs baseline: 1.0693x; 1.0295x over previous
//
#include <hip/hip_runtime.h>

// Problem constants
#define NB 16
#define NH 96
#define NW 320
#define NCIN 32

typedef __attribute__((ext_vector_type(8))) short short8;     // 8 bf16 (4 VGPRs)
typedef __attribute__((ext_vector_type(4))) float f32x4;

__device__ inline unsigned short f2bf(float f) {
    union { float f; unsigned int u; } v; v.f = f;
    unsigned int r = v.u + 0x7FFF + ((v.u >> 16) & 1);   // RNE
    return (unsigned short)(r >> 16);
}

// ---------------------------------------------------------------------------
// Fused setup kernel.
// Blocks [0,396): weight fragments OIHW fp32 -> MFMA B-operand bf16,
//   wf[((kk*NT + nt)*64 + lane)*8 + j], oc = nt*16+(lane&15),
//   ic = ks*32+(lane>>4)*8+j  [m91-verified map]
// Blocks [396,...): scatter+cast active cells from fp32 input into the
//   (memset-zeroed) dense bf16 input. Reads ONLY active cells (~25.6 MB).
// ---------------------------------------------------------------------------
__global__ __launch_bounds__(256) void setup_all(const float* __restrict__ w1,
                                                 const float* __restrict__ w2,
                                                 const float* __restrict__ w3,
                                                 unsigned short* __restrict__ f1,
                                                 unsigned short* __restrict__ f2,
                                                 unsigned short* __restrict__ f3,
                                                 const int* __restrict__ coords,
                                                 const float* __restrict__ input,
                                                 unsigned short* __restrict__ inBf,
                                                 int n) {
    if (blockIdx.x < 396) {
        int i = blockIdx.x * 256 + threadIdx.x;
        if (i < 9216) {                       // conv1: IC=32 OC=32 NT=2 KS=1
            int j = i & 7, lane = (i >> 3) & 63, nt = (i >> 9) & 1, tap = i >> 10;
            int ic = ((lane >> 4) * 8) + j, oc = nt * 16 + (lane & 15);
            f1[i] = f2bf(w1[(oc * 32 + ic) * 9 + tap]);
        } else if (i < 27648) {               // conv2: IC=32 OC=64 NT=4 KS=1
            int v = i - 9216;
            int j = v & 7, lane = (v >> 3) & 63, nt = (v >> 9) & 3, tap = v >> 11;
            int ic = ((lane >> 4) * 8) + j, oc = nt * 16 + (lane & 15);
            f2[v] = f2bf(w2[(oc * 32 + ic) * 9 + tap]);
        } else if (i < 101376) {              // conv3: IC=64 OC=128 NT=8 KS=2
            int v = i - 27648;
            int j = v & 7, lane = (v >> 3) & 63, nt = (v >> 9) & 7, kk = v >> 12;
            int tap = kk >> 1, ks = kk & 1;
            int ic = ks * 32 + ((lane >> 4) * 8) + j, oc = nt * 16 + (lane & 15);
            f3[v] = f2bf(w3[(oc * 64 + ic) * 9 + tap]);
        }
    } else {
        int i = (blockIdx.x - 396) * 256 + threadIdx.x;
        if (i >= n * 4) return;
        int ci = i >> 2, q = i & 3;
        int b = coords[ci * 3 + 0], y = coords[ci * 3 + 1], x = coords[ci * 3 + 2];
        long base = ((long)((b * NH + y) * NW + x)) * NCIN + q * 8;
        const float4* src = (const float4*)(input + base);
        float4 v0 = src[0], v1 = src[1];
        union { short8 s8; unsigned short us[8]; } o;
        o.us[0] = f2bf(v0.x); o.us[1] = f2bf(v0.y); o.us[2] = f2bf(v0.z); o.us[3] = f2bf(v0.w);
        o.us[4] = f2bf(v1.x); o.us[5] = f2bf(v1.y); o.us[6] = f2bf(v1.z); o.us[7] = f2bf(v1.w);
        *(short8*)(inBf + base) = o.s8;
    }
}

// ---------------------------------------------------------------------------
// Implicit-GEMM conv 3x3 stride-2 pad-1 via bf16 MFMA (16x16x32), bf16 NHWC in.
// Each wave: one 16-position strip x NL oc-tiles. A-fragments loaded ONCE
// per ks, reused for NL*9 MFMAs. Unconditional loads, addr clamped, reg-reg
// cndmask (R8). acc indices compile-time (R4); ks loop unroll 1 (R2).
// Layouts m89/m91.
// ---------------------------------------------------------------------------
template<int IC, int OC, int NL, int IH, int IW, int OH, int OW>
__global__ __launch_bounds__(256) void conv_mfma(
    const unsigned short* __restrict__ inPtr,  // NHWC bf16
    const unsigned short* __restrict__ wfrag,  // B-fragments bf16
    const float* __restrict__ bias,
    float* __restrict__ out)                   // NHWC fp32 (pre-relu)
{
    constexpr int KS = IC / 32;
    constexpr int NT = OC / 16;
    constexpr int NG = NT / NL;                // wave-groups per strip
    constexpr int NSTRIPS = NB * OH * OW / 16;

    const int wid  = (blockIdx.x * 256 + threadIdx.x) >> 6;
    const int lane = threadIdx.x & 63;
    const int ntb  = (wid % NG) * NL;
    const int s    = wid / NG;
    if (s >= NSTRIPS) return;
    const int quad = lane >> 4;
    const int lm   = lane & 15;

    const int p0 = s * 16;
    const int posA = p0 + lm;
    const int b  = posA / (OH * OW);
    const int rr = posA % (OH * OW);
    const int oy = rr / OW, ox = rr % OW;
    const int iy0 = oy * 2 - 1, ix0 = ox * 2 - 1;

    int cell[9];
    bool okb[9];
    #pragma unroll
    for (int t9 = 0; t9 < 9; t9++) {
        const int iy = iy0 + t9 / 3;
        const int ix = ix0 + t9 % 3;
        const bool ok = (iy >= 0) && (iy < IH) && (ix >= 0) && (ix < IW);
        cell[t9] = ok ? ((b * IH + iy) * IW + ix) : 0;   // clamp addr, not load
        okb[t9] = ok;
    }

    short8 zero8;
    #pragma unroll
    for (int j = 0; j < 8; j++) zero8[j] = 0;

    f32x4 acc[NL][2];
    #pragma unroll
    for (int nl = 0; nl < NL; nl++)
        #pragma unroll
        for (int pp = 0; pp < 2; pp++)
            acc[nl][pp] = (f32x4){0.f, 0.f, 0.f, 0.f};

    #pragma unroll 1
    for (int ks = 0; ks < KS; ks++) {
        short8 av[9];
        #pragma unroll
        for (int t9 = 0; t9 < 9; t9++) {
            short8 v = *(const short8*)(inPtr + (long)cell[t9] * IC + ks * 32 + quad * 8);
            av[t9] = okb[t9] ? v : zero8;      // reg-reg cndmask
        }
        #pragma unroll
        for (int nl = 0; nl < NL; nl++) {
            #pragma unroll
            for (int t9 = 0; t9 < 9; t9++) {
                short8 bf = *(const short8*)(wfrag + (((t9 * KS + ks) * NT + ntb + nl) * 64 + lane) * 8);
                if (t9 & 1) acc[nl][1] = __builtin_amdgcn_mfma_f32_16x16x32_bf16(av[t9], bf, acc[nl][1], 0, 0, 0);
                else        acc[nl][0] = __builtin_amdgcn_mfma_f32_16x16x32_bf16(av[t9], bf, acc[nl][0], 0, 0, 0);
            }
        }
    }

    const long rowBase = (long)p0 + quad * 4;   // D: row=(lane>>4)*4+reg
    #pragma unroll
    for (int nl = 0; nl < NL; nl++) {
        const int oc = (ntb + nl) * 16 + lm;
        const float bv = bias[oc];
        #pragma unroll
        for (int reg = 0; reg < 4; reg++)
            out[(rowBase + reg) * OC + oc] = acc[nl][0][reg] + acc[nl][1][reg] + bv;
    }
}

// ---------------------------------------------------------------------------
// 3x3 stride-1 pad-1 maxpool (-inf pad) + ReLU, NHWC. fp32 in; bf16 or fp32 out.
// ---------------------------------------------------------------------------
template<int C, int HH, int WW, bool BF16OUT>
__global__ __launch_bounds__(256) void maxpool3_relu(const float* __restrict__ in, void* __restrict__ outv) {
    constexpr int C4 = C / 4;
    int i = blockIdx.x * blockDim.x + threadIdx.x;
    if (i >= NB * HH * WW * C4) return;
    int c = i % C4;
    int x = (i / C4) % WW;
    int y = (i / (C4 * WW)) % HH;
    int b = i / (C4 * WW * HH);
    float4 m = make_float4(-3.0e38f, -3.0e38f, -3.0e38f, -3.0e38f);
    #pragma unroll
    for (int dy = -1; dy <= 1; dy++) {
        int yy = y + dy;
        if (yy < 0 || yy >= HH) continue;
        #pragma unroll
        for (int dx = -1; dx <= 1; dx++) {
            int xx = x + dx;
            if (xx < 0 || xx >= WW) continue;
            float4 v = ((const float4*)in)[((b * HH + yy) * WW + xx) * C4 + c];
            m.x = fmaxf(m.x, v.x);
            m.y = fmaxf(m.y, v.y);
            m.z = fmaxf(m.z, v.z);
            m.w = fmaxf(m.w, v.w);
        }
    }
    m.x = fmaxf(m.x, 0.f);
    m.y = fmaxf(m.y, 0.f);
    m.z = fmaxf(m.z, 0.f);
    m.w = fmaxf(m.w, 0.f);
    if (BF16OUT) {
        ushort4 o;
        o.x = f2bf(m.x); o.y = f2bf(m.y); o.z = f2bf(m.z); o.w = f2bf(m.w);
        ((ushort4*)outv)[i] = o;
    } else {
        ((float4*)outv)[i] = m;
    }
}

// ---------------------------------------------------------------------------
// LDS-tiled permute: in[b][pos][c] (NHWC pooled3 fp32, pos=480,c=128) ->
// xT[c*480+pos][b]. Both sides coalesced float4.
// ---------------------------------------------------------------------------
__global__ __launch_bounds__(256) void transpose_fc(const float* __restrict__ in, float* __restrict__ xT) {
    __shared__ float tile_s[32 * 16 * 17];    // [c_l][pos_l][b(pad 17)]
    const int pt = blockIdx.x % 30;
    const int ct = blockIdx.x / 30;
    const int pos0 = pt * 16, c0 = ct * 32;
    const int t = threadIdx.x;
    {
        const int b = t / 16, pl = t % 16;
        const float4* src = (const float4*)(in + ((long)(b * 480 + pos0 + pl)) * 128 + c0);
        #pragma unroll
        for (int q = 0; q < 8; q++) {
            float4 v = src[q];
            tile_s[((4 * q + 0) * 16 + pl) * 17 + b] = v.x;
            tile_s[((4 * q + 1) * 16 + pl) * 17 + b] = v.y;
            tile_s[((4 * q + 2) * 16 + pl) * 17 + b] = v.z;
            tile_s[((4 * q + 3) * 16 + pl) * 17 + b] = v.w;
        }
    }
    __syncthreads();
    {
        const int w = t / 64, l = t % 64;
        const int pl2 = l / 4, b4 = l % 4;
        #pragma unroll
        for (int i = 0; i < 8; i++) {
            int cl = w + 4 * i;
            const float* ls = &tile_s[(cl * 16 + pl2) * 17 + 4 * b4];
            float4 v = make_float4(ls[0], ls[1], ls[2], ls[3]);
            *(float4*)(xT + ((long)(c0 + cl) * 480 + pos0 + pl2) * 16 + 4 * b4) = v;
        }
    }
}

// ---------------------------------------------------------------------------
// FC stage 1: 64 oc-tiles x 30 k-chunks (KC=2048) = 1920 blocks.
// Inner loop = R11's proven 40-us structure: one k per thread per iter
// (scalar fw loads, xT float4s at 64-B lane stride), 8 small iterations with
// unroll 2 so the compiler software-pipelines loads across iterations.
// R12/R13 post-mortem: consecutive-k-per-thread (t*4) + unroll-1 big
// iterations broke pipelining (4 full latency exposures) and widened the xT
// scatter -- 61 us. Epilogue: 6-step __shfl_xor butterfly (compile-time
// indices), 1 KB LDS wave-fold -- R13's fix, kept.
// ---------------------------------------------------------------------------
__global__ __launch_bounds__(256) void fc_stage1(const float* __restrict__ xT,
                                                 const float* __restrict__ fw,
                                                 float* __restrict__ partial)
{
    __shared__ float red[4 * 64];              // [wave][element]
    const int tile  = blockIdx.x / 30;
    const int chunk = blockIdx.x % 30;
    const int t = threadIdx.x;
    const int wave = t >> 6;
    const int lane = t & 63;
    const int K = 61440, KC = 2048;

    float acc[4][16];
    #pragma unroll
    for (int o = 0; o < 4; o++)
        #pragma unroll
        for (int bb = 0; bb < 16; bb++) acc[o][bb] = 0.f;

    const int k0 = chunk * KC;
    #pragma unroll 2
    for (int k = k0 + t; k < k0 + KC; k += 256) {      // 8 iterations
        const float4* xp = (const float4*)(xT + (long)k * 16);
        float4 x0 = xp[0], x1 = xp[1], x2 = xp[2], x3 = xp[3];
        #pragma unroll
        for (int o = 0; o < 4; o++) {
            float w = fw[(long)(tile * 4 + o) * K + k];
            acc[o][0]  = fmaf(w, x0.x, acc[o][0]);
            acc[o][1]  = fmaf(w, x0.y, acc[o][1]);
            acc[o][2]  = fmaf(w, x0.z, acc[o][2]);
            acc[o][3]  = fmaf(w, x0.w, acc[o][3]);
            acc[o][4]  = fmaf(w, x1.x, acc[o][4]);
            acc[o][5]  = fmaf(w, x1.y, acc[o][5]);
            acc[o][6]  = fmaf(w, x1.z, acc[o][6]);
            acc[o][7]  = fmaf(w, x1.w, acc[o][7]);
            acc[o][8]  = fmaf(w, x2.x, acc[o][8]);
            acc[o][9]  = fmaf(w, x2.y, acc[o][9]);
            acc[o][10] = fmaf(w, x2.z, acc[o][10]);
            acc[o][11] = fmaf(w, x2.w, acc[o][11]);
            acc[o][12] = fmaf(w, x3.x, acc[o][12]);
            acc[o][13] = fmaf(w, x3.y, acc[o][13]);
            acc[o][14] = fmaf(w, x3.z, acc[o][14]);
            acc[o][15] = fmaf(w, x3.w, acc[o][15]);
        }
    }

    // butterfly reduce each acc element over the 64 lanes (compile-time idx)
    #pragma unroll
    for (int o = 0; o < 4; o++)
        #pragma unroll
        for (int bb = 0; bb < 16; bb++) {
            float v = acc[o][bb];
            v += __shfl_xor(v, 1);
            v += __shfl_xor(v, 2);
            v += __shfl_xor(v, 4);
            v += __shfl_xor(v, 8);
            v += __shfl_xor(v, 16);
            v += __shfl_xor(v, 32);
            acc[o][bb] = v;
        }
    if (lane == 0) {
        #pragma unroll
        for (int o = 0; o < 4; o++)
            #pragma unroll
            for (int bb = 0; bb < 16; bb++)
                red[wave * 64 + o * 16 + bb] = acc[o][bb];
    }
    __syncthreads();
    if (t < 64) {
        float s = red[t] + red[64 + t] + red[128 + t] + red[192 + t];
        int o = t / 16, bb = t % 16;
        partial[((long)chunk * 256 + tile * 4 + o) * 16 + bb] = s;
    }
}

__global__ __launch_bounds__(256) void fc_reduce(const float* __restrict__ partial,
                                                 const float* __restrict__ fcb,
                                                 float* __restrict__ out)
{
    int i = blockIdx.x * blockDim.x + threadIdx.x;   // 4096
    if (i >= 4096) return;
    int oc = i / 16, b = i % 16;
    float s = fcb[oc];
    #pragma unroll
    for (int c = 0; c < 30; c++) s += partial[(c * 256 + oc) * 16 + b];
    out[b * 256 + oc] = fmaxf(s, 0.f);
}

// ---------------------------------------------------------------------------
extern "C" void kernel_launch(void* const* d_in, const int* in_sizes, int n_in,
                              void* d_out, int out_size, void* d_ws, size_t ws_size,
                              hipStream_t stream) {
    const float* input  = (const float*)d_in[0];
    const int*   coords = (const int*)d_in[1];
    const float* w1 = (const float*)d_in[2];
    const float* b1 = (const float*)d_in[3];
    const float* w2 = (const float*)d_in[4];
    const float* b2 = (const float*)d_in[5];
    const float* w3 = (const float*)d_in[6];
    const float* b3 = (const float*)d_in[7];
    const float* fcw = (const float*)d_in[8];
    const float* fcb = (const float*)d_in[9];
    float* outp = (float*)d_out;

    const int n_active = in_sizes[1] / 3;

    // ---- workspace layout (~56 MB total) ----
    char* ws = (char*)d_ws;
    unsigned short* wf1 = (unsigned short*)ws;            // 18,432 B
    unsigned short* wf2 = wf1 + 9216;                     // 36,864 B
    unsigned short* wf3 = wf2 + 18432;                    // 147,456 B
    unsigned short* inBf = (unsigned short*)(ws + 204800);        // 31,457,280 B (16*96*320*32 bf16)
    char* regA = ws + 204800 + 31457280;                  // 15,728,640 B
    char* regB = regA + 15728640;                         // 7,864,320 B
    float* partial = (float*)(regB + 7864320);            // 491,520 B (30*256*16 fp32)

    // ping-pong aliasing (stream-ordered, each buffer dead before reuse):
    float*          conv1o  = (float*)regA;           // 15.73 MB fp32
    unsigned short* pool1bf = (unsigned short*)regB;   //  7.86 MB bf16
    float*          conv2o  = (float*)regA;           //  7.86 MB fp32
    unsigned short* pool2bf = (unsigned short*)regB;   //  3.93 MB bf16
    float*          conv3o  = (float*)regA;           //  3.93 MB fp32
    float*          pool3f  = (float*)regB;           //  3.93 MB fp32
    float*          xT      = (float*)regA;           //  3.93 MB fp32

    // zero dense bf16 input, then fused wfrag-prep + scatter-cast.
    hipMemsetAsync(inBf, 0, 31457280, stream);
    const int scatterBlocks = (n_active * 4 + 255) / 256;
    setup_all<<<396 + scatterBlocks, 256, 0, stream>>>(w1, w2, w3, wf1, wf2, wf3,
                                                       coords, input, inBf, n_active);

    // conv1: (16,96,320,32)->(16,48,160,32); NT=2 NL=2 -> 7680 waves
    conv_mfma<32, 32, 2, 96, 320, 48, 160>
        <<<1920, 256, 0, stream>>>(inBf, wf1, b1, conv1o);
    maxpool3_relu<32, 48, 160, true><<<3840, 256, 0, stream>>>(conv1o, pool1bf);

    // conv2: (16,48,160,32)->(16,24,80,64); NT=4 NL=2 -> 3840 waves
    conv_mfma<32, 64, 2, 48, 160, 24, 80>
        <<<960, 256, 0, stream>>>(pool1bf, wf2, b2, conv2o);
    maxpool3_relu<64, 24, 80, true><<<1920, 256, 0, stream>>>(conv2o, pool2bf);

    // conv3: (16,24,80,64)->(16,12,40,128); NT=8 NL=2 -> 1920 waves
    conv_mfma<64, 128, 2, 24, 80, 12, 40>
        <<<480, 256, 0, stream>>>(pool2bf, wf3, b3, conv3o);
    maxpool3_relu<128, 12, 40, false><<<960, 256, 0, stream>>>(conv3o, pool3f);

    // flatten permute + FC (fp32, exact weights)
    transpose_fc<<<120, 256, 0, stream>>>(pool3f, xT);
    fc_stage1<<<1920, 256, 0, stream>>>(xT, fcw, partial);
    fc_reduce<<<16, 256, 0, stream>>>(partial, fcb, outp);
}

// Round 15
// 254.715 us; speedup vs baseline: 1.0702x; 1.0008x over previous
//
#include <hip/hip_runtime.h>

// Problem constants
#define NB 16
#define NH 96
#define NW 320
#define NCIN 32

typedef __attribute__((ext_vector_type(8))) short short8;     // 8 bf16 (4 VGPRs)
typedef __attribute__((ext_vector_type(4))) float f32x4;

__device__ inline unsigned short f2bf(float f) {
    union { float f; unsigned int u; } v; v.f = f;
    unsigned int r = v.u + 0x7FFF + ((v.u >> 16) & 1);   // RNE
    return (unsigned short)(r >> 16);
}

// ---------------------------------------------------------------------------
// Fused setup kernel.
// Blocks [0,396): weight fragments OIHW fp32 -> MFMA B-operand bf16,
//   wf[((kk*NT + nt)*64 + lane)*8 + j], oc = nt*16+(lane&15),
//   ic = ks*32+(lane>>4)*8+j  [m91-verified map]
// Blocks [396,...): scatter+cast active cells from fp32 input into the
//   (memset-zeroed) dense bf16 input. Reads ONLY active cells (~25.6 MB).
// ---------------------------------------------------------------------------
__global__ __launch_bounds__(256) void setup_all(const float* __restrict__ w1,
                                                 const float* __restrict__ w2,
                                                 const float* __restrict__ w3,
                                                 unsigned short* __restrict__ f1,
                                                 unsigned short* __restrict__ f2,
                                                 unsigned short* __restrict__ f3,
                                                 const int* __restrict__ coords,
                                                 const float* __restrict__ input,
                                                 unsigned short* __restrict__ inBf,
                                                 int n) {
    if (blockIdx.x < 396) {
        int i = blockIdx.x * 256 + threadIdx.x;
        if (i < 9216) {                       // conv1: IC=32 OC=32 NT=2 KS=1
            int j = i & 7, lane = (i >> 3) & 63, nt = (i >> 9) & 1, tap = i >> 10;
            int ic = ((lane >> 4) * 8) + j, oc = nt * 16 + (lane & 15);
            f1[i] = f2bf(w1[(oc * 32 + ic) * 9 + tap]);
        } else if (i < 27648) {               // conv2: IC=32 OC=64 NT=4 KS=1
            int v = i - 9216;
            int j = v & 7, lane = (v >> 3) & 63, nt = (v >> 9) & 3, tap = v >> 11;
            int ic = ((lane >> 4) * 8) + j, oc = nt * 16 + (lane & 15);
            f2[v] = f2bf(w2[(oc * 32 + ic) * 9 + tap]);
        } else if (i < 101376) {              // conv3: IC=64 OC=128 NT=8 KS=2
            int v = i - 27648;
            int j = v & 7, lane = (v >> 3) & 63, nt = (v >> 9) & 7, kk = v >> 12;
            int tap = kk >> 1, ks = kk & 1;
            int ic = ks * 32 + ((lane >> 4) * 8) + j, oc = nt * 16 + (lane & 15);
            f3[v] = f2bf(w3[(oc * 64 + ic) * 9 + tap]);
        }
    } else {
        int i = (blockIdx.x - 396) * 256 + threadIdx.x;
        if (i >= n * 4) return;
        int ci = i >> 2, q = i & 3;
        int b = coords[ci * 3 + 0], y = coords[ci * 3 + 1], x = coords[ci * 3 + 2];
        long base = ((long)((b * NH + y) * NW + x)) * NCIN + q * 8;
        const float4* src = (const float4*)(input + base);
        float4 v0 = src[0], v1 = src[1];
        union { short8 s8; unsigned short us[8]; } o;
        o.us[0] = f2bf(v0.x); o.us[1] = f2bf(v0.y); o.us[2] = f2bf(v0.z); o.us[3] = f2bf(v0.w);
        o.us[4] = f2bf(v1.x); o.us[5] = f2bf(v1.y); o.us[6] = f2bf(v1.z); o.us[7] = f2bf(v1.w);
        *(short8*)(inBf + base) = o.s8;
    }
}

// ---------------------------------------------------------------------------
// Implicit-GEMM conv 3x3 stride-2 pad-1 via bf16 MFMA (16x16x32), bf16 NHWC in.
// Each wave: one 16-position strip x NL oc-tiles. A-fragments loaded ONCE
// per ks, reused for NL*9 MFMAs. Unconditional loads, addr clamped, reg-reg
// cndmask (R8). acc indices compile-time (R4); ks loop unroll 1 (R2).
// Layouts m89/m91.
// ---------------------------------------------------------------------------
template<int IC, int OC, int NL, int IH, int IW, int OH, int OW>
__global__ __launch_bounds__(256) void conv_mfma(
    const unsigned short* __restrict__ inPtr,  // NHWC bf16
    const unsigned short* __restrict__ wfrag,  // B-fragments bf16
    const float* __restrict__ bias,
    float* __restrict__ out)                   // NHWC fp32 (pre-relu)
{
    constexpr int KS = IC / 32;
    constexpr int NT = OC / 16;
    constexpr int NG = NT / NL;                // wave-groups per strip
    constexpr int NSTRIPS = NB * OH * OW / 16;

    const int wid  = (blockIdx.x * 256 + threadIdx.x) >> 6;
    const int lane = threadIdx.x & 63;
    const int ntb  = (wid % NG) * NL;
    const int s    = wid / NG;
    if (s >= NSTRIPS) return;
    const int quad = lane >> 4;
    const int lm   = lane & 15;

    const int p0 = s * 16;
    const int posA = p0 + lm;
    const int b  = posA / (OH * OW);
    const int rr = posA % (OH * OW);
    const int oy = rr / OW, ox = rr % OW;
    const int iy0 = oy * 2 - 1, ix0 = ox * 2 - 1;

    int cell[9];
    bool okb[9];
    #pragma unroll
    for (int t9 = 0; t9 < 9; t9++) {
        const int iy = iy0 + t9 / 3;
        const int ix = ix0 + t9 % 3;
        const bool ok = (iy >= 0) && (iy < IH) && (ix >= 0) && (ix < IW);
        cell[t9] = ok ? ((b * IH + iy) * IW + ix) : 0;   // clamp addr, not load
        okb[t9] = ok;
    }

    short8 zero8;
    #pragma unroll
    for (int j = 0; j < 8; j++) zero8[j] = 0;

    f32x4 acc[NL][2];
    #pragma unroll
    for (int nl = 0; nl < NL; nl++)
        #pragma unroll
        for (int pp = 0; pp < 2; pp++)
            acc[nl][pp] = (f32x4){0.f, 0.f, 0.f, 0.f};

    #pragma unroll 1
    for (int ks = 0; ks < KS; ks++) {
        short8 av[9];
        #pragma unroll
        for (int t9 = 0; t9 < 9; t9++) {
            short8 v = *(const short8*)(inPtr + (long)cell[t9] * IC + ks * 32 + quad * 8);
            av[t9] = okb[t9] ? v : zero8;      // reg-reg cndmask
        }
        #pragma unroll
        for (int nl = 0; nl < NL; nl++) {
            #pragma unroll
            for (int t9 = 0; t9 < 9; t9++) {
                short8 bf = *(const short8*)(wfrag + (((t9 * KS + ks) * NT + ntb + nl) * 64 + lane) * 8);
                if (t9 & 1) acc[nl][1] = __builtin_amdgcn_mfma_f32_16x16x32_bf16(av[t9], bf, acc[nl][1], 0, 0, 0);
                else        acc[nl][0] = __builtin_amdgcn_mfma_f32_16x16x32_bf16(av[t9], bf, acc[nl][0], 0, 0, 0);
            }
        }
    }

    const long rowBase = (long)p0 + quad * 4;   // D: row=(lane>>4)*4+reg
    #pragma unroll
    for (int nl = 0; nl < NL; nl++) {
        const int oc = (ntb + nl) * 16 + lm;
        const float bv = bias[oc];
        #pragma unroll
        for (int reg = 0; reg < 4; reg++)
            out[(rowBase + reg) * OC + oc] = acc[nl][0][reg] + acc[nl][1][reg] + bv;
    }
}

// ---------------------------------------------------------------------------
// 3x3 stride-1 pad-1 maxpool (-inf pad) + ReLU, NHWC. fp32 in; bf16 or fp32 out.
// ---------------------------------------------------------------------------
template<int C, int HH, int WW, bool BF16OUT>
__global__ __launch_bounds__(256) void maxpool3_relu(const float* __restrict__ in, void* __restrict__ outv) {
    constexpr int C4 = C / 4;
    int i = blockIdx.x * blockDim.x + threadIdx.x;
    if (i >= NB * HH * WW * C4) return;
    int c = i % C4;
    int x = (i / C4) % WW;
    int y = (i / (C4 * WW)) % HH;
    int b = i / (C4 * WW * HH);
    float4 m = make_float4(-3.0e38f, -3.0e38f, -3.0e38f, -3.0e38f);
    #pragma unroll
    for (int dy = -1; dy <= 1; dy++) {
        int yy = y + dy;
        if (yy < 0 || yy >= HH) continue;
        #pragma unroll
        for (int dx = -1; dx <= 1; dx++) {
            int xx = x + dx;
            if (xx < 0 || xx >= WW) continue;
            float4 v = ((const float4*)in)[((b * HH + yy) * WW + xx) * C4 + c];
            m.x = fmaxf(m.x, v.x);
            m.y = fmaxf(m.y, v.y);
            m.z = fmaxf(m.z, v.z);
            m.w = fmaxf(m.w, v.w);
        }
    }
    m.x = fmaxf(m.x, 0.f);
    m.y = fmaxf(m.y, 0.f);
    m.z = fmaxf(m.z, 0.f);
    m.w = fmaxf(m.w, 0.f);
    if (BF16OUT) {
        ushort4 o;
        o.x = f2bf(m.x); o.y = f2bf(m.y); o.z = f2bf(m.z); o.w = f2bf(m.w);
        ((ushort4*)outv)[i] = o;
    } else {
        ((float4*)outv)[i] = m;
    }
}

// ---------------------------------------------------------------------------
// LDS-tiled permute + bf16 cast: pooled3 NHWC fp32 (b,pos,c; pos=480,c=128)
// -> xb[b][k] bf16, k = c*480 + pos (NCHW flatten order). Coalesced float4
// reads; 16-pos (32 B) bf16 write segments.
// ---------------------------------------------------------------------------
__global__ __launch_bounds__(256) void transpose_fc(const float* __restrict__ in,
                                                    unsigned short* __restrict__ xb) {
    __shared__ float tile_s[32 * 16 * 17];    // [c_l][pos_l][b(pad 17)]
    const int pt = blockIdx.x % 30;
    const int ct = blockIdx.x / 30;
    const int pos0 = pt * 16, c0 = ct * 32;
    const int t = threadIdx.x;
    {
        const int b = t / 16, pl = t % 16;
        const float4* src = (const float4*)(in + ((long)(b * 480 + pos0 + pl)) * 128 + c0);
        #pragma unroll
        for (int q = 0; q < 8; q++) {
            float4 v = src[q];
            tile_s[((4 * q + 0) * 16 + pl) * 17 + b] = v.x;
            tile_s[((4 * q + 1) * 16 + pl) * 17 + b] = v.y;
            tile_s[((4 * q + 2) * 16 + pl) * 17 + b] = v.z;
            tile_s[((4 * q + 3) * 16 + pl) * 17 + b] = v.w;
        }
    }
    __syncthreads();
    {
        // 512 (b, c_l) segments of 16 pos; each thread writes 2 segments
        #pragma unroll
        for (int r = 0; r < 2; r++) {
            int seg = t * 2 + r;
            int b = seg / 32, cl = seg % 32;
            union { short8 s8; unsigned short us[8]; } o0, o1;
            #pragma unroll
            for (int pl = 0; pl < 8; pl++)
                o0.us[pl] = f2bf(tile_s[(cl * 16 + pl) * 17 + b]);
            #pragma unroll
            for (int pl = 0; pl < 8; pl++)
                o1.us[pl] = f2bf(tile_s[(cl * 16 + 8 + pl) * 17 + b]);
            unsigned short* dst = xb + (long)b * 61440 + (c0 + cl) * 480 + pos0;
            *(short8*)dst = o0.s8;
            *(short8*)(dst + 8) = o1.s8;
        }
    }
}

// ---------------------------------------------------------------------------
// FC via MFMA: C[16,256] = x[16,61440] . fcw^T. Wave = one 16-oc tile x one
// 256-k chunk; 16 tiles x 240 chunks = 3840 waves = 960 blocks. Per 32-k
// step: A-frag 16 B/lane from xb[b][k] (m=lane&15=batch, k=quad*8+j); B-frag
// = 2 float4 from the fp32 fcw row (n=lane&15=oc), RNE-converted in-register;
// 1 MFMA (2 chained accs). D-layout gives each lane its own (b,oc) outputs:
// NO cross-lane reduction -- R14 post-mortem showed the butterfly epilogue
// (~768 VALU/wave) + 512 scalar FMAs were the instruction-rate wall.
// fcw streams once as fp32 (no prepack traffic).
// ---------------------------------------------------------------------------
__global__ __launch_bounds__(256) void fc_mfma(const unsigned short* __restrict__ xb,
                                               const float* __restrict__ fw,
                                               float* __restrict__ partial)
{
    const int wid  = (blockIdx.x * 256 + threadIdx.x) >> 6;   // 0..3839
    const int lane = threadIdx.x & 63;
    const int tile  = wid / 240;        // 0..15
    const int chunk = wid % 240;        // 0..239
    const int quad = lane >> 4;
    const int lm   = lane & 15;
    const int K = 61440;
    const int k0 = chunk * 256;

    const unsigned short* xrow = xb + (long)lm * K;           // batch row (A)
    const float* wrow = fw + (long)(tile * 16 + lm) * K;      // oc row (B)

    f32x4 acc0 = {0.f, 0.f, 0.f, 0.f};
    f32x4 acc1 = {0.f, 0.f, 0.f, 0.f};
    #pragma unroll
    for (int st = 0; st < 8; st++) {
        const int k = k0 + st * 32 + quad * 8;
        short8 a = *(const short8*)(xrow + k);
        float4 w0 = *(const float4*)(wrow + k);
        float4 w1 = *(const float4*)(wrow + k + 4);
        union { short8 s8; unsigned short us[8]; } bb;
        bb.us[0] = f2bf(w0.x); bb.us[1] = f2bf(w0.y);
        bb.us[2] = f2bf(w0.z); bb.us[3] = f2bf(w0.w);
        bb.us[4] = f2bf(w1.x); bb.us[5] = f2bf(w1.y);
        bb.us[6] = f2bf(w1.z); bb.us[7] = f2bf(w1.w);
        if (st & 1) acc1 = __builtin_amdgcn_mfma_f32_16x16x32_bf16(a, bb.s8, acc1, 0, 0, 0);
        else        acc0 = __builtin_amdgcn_mfma_f32_16x16x32_bf16(a, bb.s8, acc0, 0, 0, 0);
    }

    // D: row(m=batch) = quad*4+reg, col(n=oc) = lm
    #pragma unroll
    for (int reg = 0; reg < 4; reg++) {
        float v = acc0[reg] + acc1[reg];
        partial[((long)chunk * 256 + tile * 16 + lm) * 16 + quad * 4 + reg] = v;
    }
}

__global__ __launch_bounds__(256) void fc_reduce(const float* __restrict__ partial,
                                                 const float* __restrict__ fcb,
                                                 float* __restrict__ out)
{
    int i = blockIdx.x * blockDim.x + threadIdx.x;   // 4096
    if (i >= 4096) return;
    int oc = i / 16, b = i % 16;
    float s = fcb[oc];
    #pragma unroll 4
    for (int c = 0; c < 240; c++) s += partial[((long)c * 256 + oc) * 16 + b];
    out[b * 256 + oc] = fmaxf(s, 0.f);
}

// ---------------------------------------------------------------------------
extern "C" void kernel_launch(void* const* d_in, const int* in_sizes, int n_in,
                              void* d_out, int out_size, void* d_ws, size_t ws_size,
                              hipStream_t stream) {
    const float* input  = (const float*)d_in[0];
    const int*   coords = (const int*)d_in[1];
    const float* w1 = (const float*)d_in[2];
    const float* b1 = (const float*)d_in[3];
    const float* w2 = (const float*)d_in[4];
    const float* b2 = (const float*)d_in[5];
    const float* w3 = (const float*)d_in[6];
    const float* b3 = (const float*)d_in[7];
    const float* fcw = (const float*)d_in[8];
    const float* fcb = (const float*)d_in[9];
    float* outp = (float*)d_out;

    const int n_active = in_sizes[1] / 3;

    // ---- workspace layout (~59 MB total) ----
    char* ws = (char*)d_ws;
    unsigned short* wf1 = (unsigned short*)ws;            // 18,432 B
    unsigned short* wf2 = wf1 + 9216;                     // 36,864 B
    unsigned short* wf3 = wf2 + 18432;                    // 147,456 B
    unsigned short* inBf = (unsigned short*)(ws + 204800);        // 31,457,280 B (16*96*320*32 bf16)
    char* regA = ws + 204800 + 31457280;                  // 15,728,640 B
    char* regB = regA + 15728640;                         // 7,864,320 B
    float* partial = (float*)(regB + 7864320);            // 3,932,160 B (240*256*16 fp32)

    // ping-pong aliasing (stream-ordered, each buffer dead before reuse):
    float*          conv1o  = (float*)regA;           // 15.73 MB fp32
    unsigned short* pool1bf = (unsigned short*)regB;   //  7.86 MB bf16
    float*          conv2o  = (float*)regA;           //  7.86 MB fp32
    unsigned short* pool2bf = (unsigned short*)regB;   //  3.93 MB bf16
    float*          conv3o  = (float*)regA;           //  3.93 MB fp32
    float*          pool3f  = (float*)regB;           //  3.93 MB fp32
    unsigned short* xb      = (unsigned short*)regA;   //  1.97 MB bf16 [b][k]

    // zero dense bf16 input, then fused wfrag-prep + scatter-cast.
    hipMemsetAsync(inBf, 0, 31457280, stream);
    const int scatterBlocks = (n_active * 4 + 255) / 256;
    setup_all<<<396 + scatterBlocks, 256, 0, stream>>>(w1, w2, w3, wf1, wf2, wf3,
                                                       coords, input, inBf, n_active);

    // conv1: (16,96,320,32)->(16,48,160,32); NT=2 NL=2 -> 7680 waves
    conv_mfma<32, 32, 2, 96, 320, 48, 160>
        <<<1920, 256, 0, stream>>>(inBf, wf1, b1, conv1o);
    maxpool3_relu<32, 48, 160, true><<<3840, 256, 0, stream>>>(conv1o, pool1bf);

    // conv2: (16,48,160,32)->(16,24,80,64); NT=4 NL=2 -> 3840 waves
    conv_mfma<32, 64, 2, 48, 160, 24, 80>
        <<<960, 256, 0, stream>>>(pool1bf, wf2, b2, conv2o);
    maxpool3_relu<64, 24, 80, true><<<1920, 256, 0, stream>>>(conv2o, pool2bf);

    // conv3: (16,24,80,64)->(16,12,40,128); NT=8 NL=2 -> 1920 waves
    conv_mfma<64, 128, 2, 24, 80, 12, 40>
        <<<480, 256, 0, stream>>>(pool2bf, wf3, b3, conv3o);
    maxpool3_relu<128, 12, 40, false><<<960, 256, 0, stream>>>(conv3o, pool3f);

    // flatten permute (fp32 -> bf16 [b][k]) + MFMA FC
    transpose_fc<<<120, 256, 0, stream>>>(pool3f, xb);
    fc_mfma<<<960, 256, 0, stream>>>(xb, fcw, partial);
    fc_reduce<<<16, 256, 0, stream>>>(partial, fcb, outp);
}